// Round 1
// baseline (372.180 us; speedup 1.0000x reference)
//
#include <hip/hip_runtime.h>
#include <stdint.h>

#define M_ROWS 4096
#define N_COLS 16384
#define K_HARD 163          // int(0.01 * (16384 - 1))
#define DELTA_W 5.0f
#define BLOCK  256
#define CAP    1024         // compacted cap (mean 373, sd 19 -> >CAP is ~34 sigma)
#define NB     1024         // histogram bins
#define SMALL  64           // pivot-bin resolve cap (expect ~2)
#define THRESH 2.0f
#define KEY_MIN 0xC0000000u // f2key(2.0f)

__device__ __forceinline__ uint32_t f2key(float x) {
    uint32_t u = __float_as_uint(x);
    return u ^ (uint32_t)(((int32_t)u >> 31) | 0x80000000u);
}
__device__ __forceinline__ float key2f(uint32_t k) {
    uint32_t u = (k & 0x80000000u) ? (k & 0x7fffffffu) : ~k;
    return __uint_as_float(u);
}
__device__ __forceinline__ float softplus_f(float x) {
    return fmaxf(x, 0.0f) + log1pf(__expf(-fabsf(x)));
}

// fallback-only parallel pivot finder over NB ascending bins
__device__ void pivot_scan(const uint32_t* hist, int K,
                           int* part, int* pivot, int* krem) {
    const int t = threadIdx.x;
    const int bpt = NB / BLOCK;            // 4
    const int base = t * bpt;
    int mypart = 0;
    for (int i = 0; i < bpt; ++i) mypart += (int)hist[base + i];
    part[t] = mypart;
    __syncthreads();
    for (int off = 1; off < BLOCK; off <<= 1) {
        int v = part[t];
        if (t + off < BLOCK) v += part[t + off];
        __syncthreads();
        part[t] = v;
        __syncthreads();
    }
    const int above = part[t] - mypart;
    if (above < K && above + mypart >= K) {
        int running = above;
        for (int b = base + bpt - 1; b >= base; --b) {
            int c = (int)hist[b];
            if (running < K && running + c >= K) { *pivot = b; *krem = K - running; }
            running += c;
        }
    }
    __syncthreads();
}

// candidate-sparse: only ~2.3% of elements take this path
#define PROCESS4(v)                                                            \
    do {                                                                       \
        const bool b0 = ((v).x >= THRESH);                                     \
        const bool b1 = ((v).y >= THRESH);                                     \
        const bool b2 = ((v).z >= THRESH);                                     \
        const bool b3 = ((v).w >= THRESH);                                     \
        const int kk = (int)b0 + (int)b1 + (int)b2 + (int)b3;                  \
        if (kk) {                                                              \
            int d = atomicAdd(&s_cnt, kk);                                     \
            if (b0) {                                                          \
                const uint32_t key = f2key((v).x);                             \
                if (d < CAP) s_cand[d] = key;                                  \
                atomicAdd(&s_hist[min((key - KEY_MIN) >> 14,                   \
                                      (uint32_t)(NB - 1))], 1u);               \
                ++d;                                                           \
            }                                                                  \
            if (b1) {                                                          \
                const uint32_t key = f2key((v).y);                             \
                if (d < CAP) s_cand[d] = key;                                  \
                atomicAdd(&s_hist[min((key - KEY_MIN) >> 14,                   \
                                      (uint32_t)(NB - 1))], 1u);               \
                ++d;                                                           \
            }                                                                  \
            if (b2) {                                                          \
                const uint32_t key = f2key((v).z);                             \
                if (d < CAP) s_cand[d] = key;                                  \
                atomicAdd(&s_hist[min((key - KEY_MIN) >> 14,                   \
                                      (uint32_t)(NB - 1))], 1u);               \
                ++d;                                                           \
            }                                                                  \
            if (b3) {                                                          \
                const uint32_t key = f2key((v).w);                             \
                if (d < CAP) s_cand[d] = key;                                  \
                atomicAdd(&s_hist[min((key - KEY_MIN) >> 14,                   \
                                      (uint32_t)(NB - 1))], 1u);               \
                ++d;                                                           \
            }                                                                  \
        }                                                                      \
    } while (0)

__global__ __launch_bounds__(BLOCK, 4) void mmcl_kernel(
        const float* __restrict__ inputs,
        const int* __restrict__ targets,
        float* __restrict__ out) {
    __shared__ uint32_t s_cand[CAP];               // 4 KB; aliased as part in fallback
    __shared__ uint32_t s_hist[NB];                // 4 KB
    __shared__ int s_wt[4];
    __shared__ int s_cnt, s_found, s_pivot, s_krem, s_nsmall;
    __shared__ uint32_t s_skey[SMALL];
    __shared__ int s_sidx[SMALL];
    __shared__ float s_fw[4];

    const int row = blockIdx.x;
    const int t = threadIdx.x;
    const int lane = t & 63;
    const int wid = t >> 6;
    const float* rowp = inputs + (size_t)row * N_COLS;
    const int target = targets[row];
    const float pos = rowp[target];                // early: overlap latency with init

    for (int i = t; i < NB; i += BLOCK) s_hist[i] = 0;
    if (t == 0) { s_cnt = 0; s_found = -1; s_nsmall = 0; }
    __syncthreads();   // B0

    // ---- streaming: sparse predicated compaction + fused histogram ----
    // loads grouped 4x ahead of the branchy bodies so they issue before the
    // LDS atomics (guaranteed 64B/thread in flight regardless of atomic
    // ordering conservatism in the compiler).
    const float4* rp4 = (const float4*)rowp;
    for (int g = 0; g < N_COLS / (BLOCK * 16); ++g) {   // 4 groups
        const float4 v0 = rp4[(g * 4 + 0) * BLOCK + t];
        const float4 v1 = rp4[(g * 4 + 1) * BLOCK + t];
        const float4 v2 = rp4[(g * 4 + 2) * BLOCK + t];
        const float4 v3 = rp4[(g * 4 + 3) * BLOCK + t];
        PROCESS4(v0);
        PROCESS4(v1);
        PROCESS4(v2);
        PROCESS4(v3);
    }
    __syncthreads();   // B1
    const int total = s_cnt;

    // ---- remove one instance of the positive (hist decrement fused) ----
    const uint32_t tkey = f2key(pos);
    const int tclamp = min(total, CAP);
    if (pos >= THRESH) {
        for (int i = t; i < tclamp; i += BLOCK)
            if (s_cand[i] == tkey) { atomicCAS(&s_found, -1, i); break; }
    }
    __syncthreads();   // B2
    int ncand = total;
    if (s_found >= 0) {
        ncand = total - 1;
        if (t == 0) {
            if (ncand < CAP) s_cand[s_found] = s_cand[ncand];
            s_hist[min((tkey - KEY_MIN) >> 14, (uint32_t)(NB - 1))] -= 1u;
        }
    }
    __syncthreads();   // B3

    const bool fast = (total <= CAP) && (ncand >= K_HARD);
    bool needfb = !fast;
    float local = 0.0f;

    if (fast) {
        // ---- shfl suffix scan to locate pivot bin (hist already built) ----
        const int base4 = t * 4;
        const int c0 = (int)s_hist[base4], c1 = (int)s_hist[base4 + 1],
                  c2 = (int)s_hist[base4 + 2], c3 = (int)s_hist[base4 + 3];
        const int own = c0 + c1 + c2 + c3;
        int suf = own;
        for (int off = 1; off < 64; off <<= 1) {
            int y = __shfl_down(suf, off);
            if (lane + off < 64) suf += y;
        }
        if (lane == 0) s_wt[wid] = suf;      // wave total
        __syncthreads();   // B4
        int wsuf = 0;
        for (int w = wid + 1; w < 4; ++w) wsuf += s_wt[w];
        int run = wsuf + (suf - own);        // count in bins strictly above mine
        {
            const int cs[4] = {c0, c1, c2, c3};
            for (int b = 3; b >= 0; --b) {
                const int c = cs[b];
                if (run < K_HARD && run + c >= K_HARD) {
                    s_pivot = base4 + b; s_krem = K_HARD - run;
                }
                run += c;
            }
        }
        __syncthreads();   // B5
        const uint32_t B = (uint32_t)s_pivot;
        const int krem = s_krem;

        // ---- sure set + collect pivot-bin members ----
        for (int i = t; i < ncand; i += BLOCK) {
            const uint32_t k = s_cand[i];
            const uint32_t kb = min((k - KEY_MIN) >> 14, (uint32_t)(NB - 1));
            if (kb > B) local += softplus_f(key2f(k));
            else if (kb == B) {
                const int d = atomicAdd(&s_nsmall, 1);
                if (d < SMALL) { s_skey[d] = k; s_sidx[d] = i; }
            }
        }
        __syncthreads();   // B6
        const int m = s_nsmall;
        if (m > SMALL) { needfb = true; local = 0.0f; }
        else {
            // exact resolve: take krem largest (key desc, index asc) of m
            for (int i = t; i < m; i += BLOCK) {
                const uint32_t ki = s_skey[i]; const int ii = s_sidx[i];
                int r = 0;
                for (int j = 0; j < m; ++j) {
                    const uint32_t kj = s_skey[j];
                    r += (kj > ki) || (kj == ki && s_sidx[j] < ii);
                }
                if (r < krem) local += softplus_f(key2f(ki));
            }
        }
    }

    if (needfb) {
        // ---- generic exact fallback: 10+10+10+2 radix from global ----
        local = 0.0f;
        int* part = (int*)s_cand;
        uint32_t* hist = s_hist;
        for (int i = t; i < NB; i += BLOCK) hist[i] = 0;
        __syncthreads();
        for (int j = t; j < N_COLS; j += BLOCK) {
            if (j == target) continue;
            atomicAdd(&hist[f2key(rowp[j]) >> 22], 1u);
        }
        __syncthreads();
        pivot_scan(hist, K_HARD, part, &s_pivot, &s_krem);
        const int p1 = s_pivot, k1r = s_krem;

        for (int i = t; i < NB; i += BLOCK) hist[i] = 0;
        __syncthreads();
        for (int j = t; j < N_COLS; j += BLOCK) {
            if (j == target) continue;
            const uint32_t k = f2key(rowp[j]);
            if ((int)(k >> 22) == p1) atomicAdd(&hist[(k >> 12) & 1023u], 1u);
        }
        __syncthreads();
        pivot_scan(hist, k1r, part, &s_pivot, &s_krem);
        const uint32_t pref2 = ((uint32_t)p1 << 10) | (uint32_t)s_pivot;
        const int k2r = s_krem;

        for (int i = t; i < NB; i += BLOCK) hist[i] = 0;
        __syncthreads();
        for (int j = t; j < N_COLS; j += BLOCK) {
            if (j == target) continue;
            const uint32_t k = f2key(rowp[j]);
            if ((k >> 12) == pref2) atomicAdd(&hist[(k >> 2) & 1023u], 1u);
        }
        __syncthreads();
        pivot_scan(hist, k2r, part, &s_pivot, &s_krem);
        const uint32_t pref3 = (pref2 << 10) | (uint32_t)s_pivot;
        const int k3r = s_krem;

        for (int i = t; i < 4; i += BLOCK) hist[i] = 0;
        __syncthreads();
        for (int j = t; j < N_COLS; j += BLOCK) {
            if (j == target) continue;
            const uint32_t k = f2key(rowp[j]);
            if ((k >> 2) == pref3) atomicAdd(&hist[k & 3u], 1u);
        }
        __syncthreads();
        if (t == 0) {
            int running = 0;
            for (int b = 3; b >= 0; --b) {
                const int c = (int)hist[b];
                if (running < k3r && running + c >= k3r) {
                    s_pivot = b; s_krem = k3r - running;
                }
                running += c;
            }
        }
        __syncthreads();
        const uint32_t T = (pref3 << 2) | (uint32_t)s_pivot;
        const int tie = s_krem;

        for (int j = t; j < N_COLS; j += BLOCK) {
            if (j == target) continue;
            const uint32_t k = f2key(rowp[j]);
            if (k > T) local += softplus_f(key2f(k));
        }
        if (t == 0) local += (float)tie * softplus_f(key2f(T));
    }

    // ---- block reduce + epilogue ----
    for (int off = 32; off > 0; off >>= 1) local += __shfl_down(local, off);
    if (lane == 0) s_fw[wid] = local;
    __syncthreads();
    if (t == 0) {
        const float tot = s_fw[0] + s_fw[1] + s_fw[2] + s_fw[3];
        const float l_neg = tot / (float)K_HARD;
        const float l_pos = softplus_f(-pos);
        const float rowval = (DELTA_W * l_pos + l_neg) * (1.0f / (float)M_ROWS);
        atomicAdd(out, rowval);
    }
}

__global__ void mmcl_zero_out(float* out) { out[0] = 0.0f; }

extern "C" void kernel_launch(void* const* d_in, const int* in_sizes, int n_in,
                              void* d_out, int out_size, void* d_ws, size_t ws_size,
                              hipStream_t stream) {
    const float* inputs = (const float*)d_in[0];
    const int* targets = (const int*)d_in[1];
    float* out = (float*)d_out;
    mmcl_zero_out<<<1, 1, 0, stream>>>(out);
    mmcl_kernel<<<M_ROWS, BLOCK, 0, stream>>>(inputs, targets, out);
}

// Round 2
// 369.554 us; speedup vs baseline: 1.0071x; 1.0071x over previous
//
#include <hip/hip_runtime.h>
#include <stdint.h>

#define M_ROWS 4096
#define N_COLS 16384
#define K_HARD 163          // int(0.01 * (16384 - 1))
#define DELTA_W 5.0f
#define BLOCK  256
#define CAP    1024         // compacted cap (mean 373, sd 19 -> >CAP is ~34 sigma)
#define NB     1024         // histogram bins
#define SMALL  64           // pivot-bin resolve cap (expect ~2)
#define THRESH 2.0f
#define KEY_MIN 0xC0000000u // f2key(2.0f)

__device__ __forceinline__ uint32_t f2key(float x) {
    uint32_t u = __float_as_uint(x);
    return u ^ (uint32_t)(((int32_t)u >> 31) | 0x80000000u);
}
__device__ __forceinline__ float key2f(uint32_t k) {
    uint32_t u = (k & 0x80000000u) ? (k & 0x7fffffffu) : ~k;
    return __uint_as_float(u);
}
__device__ __forceinline__ float softplus_f(float x) {
    return fmaxf(x, 0.0f) + log1pf(__expf(-fabsf(x)));
}

// fallback-only parallel pivot finder over NB ascending bins
__device__ void pivot_scan(const uint32_t* hist, int K,
                           int* part, int* pivot, int* krem) {
    const int t = threadIdx.x;
    const int bpt = NB / BLOCK;            // 4
    const int base = t * bpt;
    int mypart = 0;
    for (int i = 0; i < bpt; ++i) mypart += (int)hist[base + i];
    part[t] = mypart;
    __syncthreads();
    for (int off = 1; off < BLOCK; off <<= 1) {
        int v = part[t];
        if (t + off < BLOCK) v += part[t + off];
        __syncthreads();
        part[t] = v;
        __syncthreads();
    }
    const int above = part[t] - mypart;
    if (above < K && above + mypart >= K) {
        int running = above;
        for (int b = base + bpt - 1; b >= base; --b) {
            int c = (int)hist[b];
            if (running < K && running + c >= K) { *pivot = b; *krem = K - running; }
            running += c;
        }
    }
    __syncthreads();
}

// candidate-sparse: only ~2.3% of elements take this path
#define PROCESS4(v)                                                            \
    do {                                                                       \
        const bool b0 = ((v).x >= THRESH);                                     \
        const bool b1 = ((v).y >= THRESH);                                     \
        const bool b2 = ((v).z >= THRESH);                                     \
        const bool b3 = ((v).w >= THRESH);                                     \
        const int kk = (int)b0 + (int)b1 + (int)b2 + (int)b3;                  \
        if (kk) {                                                              \
            int d = atomicAdd(&s_cnt, kk);                                     \
            if (b0) {                                                          \
                const uint32_t key = f2key((v).x);                             \
                if (d < CAP) s_cand[d] = key;                                  \
                atomicAdd(&s_hist[min((key - KEY_MIN) >> 14,                   \
                                      (uint32_t)(NB - 1))], 1u);               \
                ++d;                                                           \
            }                                                                  \
            if (b1) {                                                          \
                const uint32_t key = f2key((v).y);                             \
                if (d < CAP) s_cand[d] = key;                                  \
                atomicAdd(&s_hist[min((key - KEY_MIN) >> 14,                   \
                                      (uint32_t)(NB - 1))], 1u);               \
                ++d;                                                           \
            }                                                                  \
            if (b2) {                                                          \
                const uint32_t key = f2key((v).z);                             \
                if (d < CAP) s_cand[d] = key;                                  \
                atomicAdd(&s_hist[min((key - KEY_MIN) >> 14,                   \
                                      (uint32_t)(NB - 1))], 1u);               \
                ++d;                                                           \
            }                                                                  \
            if (b3) {                                                          \
                const uint32_t key = f2key((v).w);                             \
                if (d < CAP) s_cand[d] = key;                                  \
                atomicAdd(&s_hist[min((key - KEY_MIN) >> 14,                   \
                                      (uint32_t)(NB - 1))], 1u);               \
                ++d;                                                           \
            }                                                                  \
        }                                                                      \
    } while (0)

__global__ __launch_bounds__(BLOCK, 4) void mmcl_kernel(
        const float* __restrict__ inputs,
        const int* __restrict__ targets,
        float* __restrict__ partials) {
    __shared__ uint32_t s_cand[CAP];               // 4 KB; aliased as part in fallback
    __shared__ uint32_t s_hist[NB];                // 4 KB
    __shared__ int s_wt[4];
    __shared__ int s_cnt, s_found, s_pivot, s_krem, s_nsmall;
    __shared__ uint32_t s_skey[SMALL];
    __shared__ int s_sidx[SMALL];
    __shared__ float s_fw[4];

    const int row = blockIdx.x;
    const int t = threadIdx.x;
    const int lane = t & 63;
    const int wid = t >> 6;
    const float* rowp = inputs + (size_t)row * N_COLS;
    const int target = targets[row];
    const float pos = rowp[target];                // early: overlap latency with init

    for (int i = t; i < NB; i += BLOCK) s_hist[i] = 0;
    if (t == 0) { s_cnt = 0; s_found = -1; s_nsmall = 0; }
    __syncthreads();   // B0

    // ---- streaming: sparse predicated compaction + fused histogram ----
    const float4* rp4 = (const float4*)rowp;
    for (int g = 0; g < N_COLS / (BLOCK * 16); ++g) {   // 4 groups
        const float4 v0 = rp4[(g * 4 + 0) * BLOCK + t];
        const float4 v1 = rp4[(g * 4 + 1) * BLOCK + t];
        const float4 v2 = rp4[(g * 4 + 2) * BLOCK + t];
        const float4 v3 = rp4[(g * 4 + 3) * BLOCK + t];
        PROCESS4(v0);
        PROCESS4(v1);
        PROCESS4(v2);
        PROCESS4(v3);
    }
    __syncthreads();   // B1
    const int total = s_cnt;

    // ---- remove one instance of the positive (hist decrement fused) ----
    const uint32_t tkey = f2key(pos);
    const int tclamp = min(total, CAP);
    if (pos >= THRESH) {
        for (int i = t; i < tclamp; i += BLOCK)
            if (s_cand[i] == tkey) { atomicCAS(&s_found, -1, i); break; }
    }
    __syncthreads();   // B2
    int ncand = total;
    if (s_found >= 0) {
        ncand = total - 1;
        if (t == 0) {
            if (ncand < CAP) s_cand[s_found] = s_cand[ncand];
            s_hist[min((tkey - KEY_MIN) >> 14, (uint32_t)(NB - 1))] -= 1u;
        }
    }
    __syncthreads();   // B3

    const bool fast = (total <= CAP) && (ncand >= K_HARD);
    bool needfb = !fast;
    float local = 0.0f;

    if (fast) {
        // ---- shfl suffix scan to locate pivot bin (hist already built) ----
        const int base4 = t * 4;
        const int c0 = (int)s_hist[base4], c1 = (int)s_hist[base4 + 1],
                  c2 = (int)s_hist[base4 + 2], c3 = (int)s_hist[base4 + 3];
        const int own = c0 + c1 + c2 + c3;
        int suf = own;
        for (int off = 1; off < 64; off <<= 1) {
            int y = __shfl_down(suf, off);
            if (lane + off < 64) suf += y;
        }
        if (lane == 0) s_wt[wid] = suf;      // wave total
        __syncthreads();   // B4
        int wsuf = 0;
        for (int w = wid + 1; w < 4; ++w) wsuf += s_wt[w];
        int run = wsuf + (suf - own);        // count in bins strictly above mine
        {
            const int cs[4] = {c0, c1, c2, c3};
            for (int b = 3; b >= 0; --b) {
                const int c = cs[b];
                if (run < K_HARD && run + c >= K_HARD) {
                    s_pivot = base4 + b; s_krem = K_HARD - run;
                }
                run += c;
            }
        }
        __syncthreads();   // B5
        const uint32_t B = (uint32_t)s_pivot;
        const int krem = s_krem;

        // ---- sure set + collect pivot-bin members ----
        for (int i = t; i < ncand; i += BLOCK) {
            const uint32_t k = s_cand[i];
            const uint32_t kb = min((k - KEY_MIN) >> 14, (uint32_t)(NB - 1));
            if (kb > B) local += softplus_f(key2f(k));
            else if (kb == B) {
                const int d = atomicAdd(&s_nsmall, 1);
                if (d < SMALL) { s_skey[d] = k; s_sidx[d] = i; }
            }
        }
        __syncthreads();   // B6
        const int m = s_nsmall;
        if (m > SMALL) { needfb = true; local = 0.0f; }
        else {
            // exact resolve: take krem largest (key desc, index asc) of m
            for (int i = t; i < m; i += BLOCK) {
                const uint32_t ki = s_skey[i]; const int ii = s_sidx[i];
                int r = 0;
                for (int j = 0; j < m; ++j) {
                    const uint32_t kj = s_skey[j];
                    r += (kj > ki) || (kj == ki && s_sidx[j] < ii);
                }
                if (r < krem) local += softplus_f(key2f(ki));
            }
        }
    }

    if (needfb) {
        // ---- generic exact fallback: 10+10+10+2 radix from global ----
        local = 0.0f;
        int* part = (int*)s_cand;
        uint32_t* hist = s_hist;
        for (int i = t; i < NB; i += BLOCK) hist[i] = 0;
        __syncthreads();
        for (int j = t; j < N_COLS; j += BLOCK) {
            if (j == target) continue;
            atomicAdd(&hist[f2key(rowp[j]) >> 22], 1u);
        }
        __syncthreads();
        pivot_scan(hist, K_HARD, part, &s_pivot, &s_krem);
        const int p1 = s_pivot, k1r = s_krem;

        for (int i = t; i < NB; i += BLOCK) hist[i] = 0;
        __syncthreads();
        for (int j = t; j < N_COLS; j += BLOCK) {
            if (j == target) continue;
            const uint32_t k = f2key(rowp[j]);
            if ((int)(k >> 22) == p1) atomicAdd(&hist[(k >> 12) & 1023u], 1u);
        }
        __syncthreads();
        pivot_scan(hist, k1r, part, &s_pivot, &s_krem);
        const uint32_t pref2 = ((uint32_t)p1 << 10) | (uint32_t)s_pivot;
        const int k2r = s_krem;

        for (int i = t; i < NB; i += BLOCK) hist[i] = 0;
        __syncthreads();
        for (int j = t; j < N_COLS; j += BLOCK) {
            if (j == target) continue;
            const uint32_t k = f2key(rowp[j]);
            if ((k >> 12) == pref2) atomicAdd(&hist[(k >> 2) & 1023u], 1u);
        }
        __syncthreads();
        pivot_scan(hist, k2r, part, &s_pivot, &s_krem);
        const uint32_t pref3 = (pref2 << 10) | (uint32_t)s_pivot;
        const int k3r = s_krem;

        for (int i = t; i < 4; i += BLOCK) hist[i] = 0;
        __syncthreads();
        for (int j = t; j < N_COLS; j += BLOCK) {
            if (j == target) continue;
            const uint32_t k = f2key(rowp[j]);
            if ((k >> 2) == pref3) atomicAdd(&hist[k & 3u], 1u);
        }
        __syncthreads();
        if (t == 0) {
            int running = 0;
            for (int b = 3; b >= 0; --b) {
                const int c = (int)hist[b];
                if (running < k3r && running + c >= k3r) {
                    s_pivot = b; s_krem = k3r - running;
                }
                running += c;
            }
        }
        __syncthreads();
        const uint32_t T = (pref3 << 2) | (uint32_t)s_pivot;
        const int tie = s_krem;

        for (int j = t; j < N_COLS; j += BLOCK) {
            if (j == target) continue;
            const uint32_t k = f2key(rowp[j]);
            if (k > T) local += softplus_f(key2f(k));
        }
        if (t == 0) local += (float)tie * softplus_f(key2f(T));
    }

    // ---- block reduce + epilogue: contention-free partial store ----
    for (int off = 32; off > 0; off >>= 1) local += __shfl_down(local, off);
    if (lane == 0) s_fw[wid] = local;
    __syncthreads();
    if (t == 0) {
        const float tot = s_fw[0] + s_fw[1] + s_fw[2] + s_fw[3];
        const float l_neg = tot / (float)K_HARD;
        const float l_pos = softplus_f(-pos);
        partials[row] = (DELTA_W * l_pos + l_neg) * (1.0f / (float)M_ROWS);
    }
}

__global__ __launch_bounds__(256) void mmcl_reduce(
        const float* __restrict__ partials, float* __restrict__ out) {
    __shared__ float sw[4];
    const int t = threadIdx.x;
    float s = 0.0f;
    for (int i = t; i < M_ROWS; i += 256) s += partials[i];
    for (int off = 32; off > 0; off >>= 1) s += __shfl_down(s, off);
    if ((t & 63) == 0) sw[t >> 6] = s;
    __syncthreads();
    if (t == 0) out[0] = sw[0] + sw[1] + sw[2] + sw[3];
}

extern "C" void kernel_launch(void* const* d_in, const int* in_sizes, int n_in,
                              void* d_out, int out_size, void* d_ws, size_t ws_size,
                              hipStream_t stream) {
    const float* inputs = (const float*)d_in[0];
    const int* targets = (const int*)d_in[1];
    float* out = (float*)d_out;
    float* partials = (float*)d_ws;   // 16 KB of workspace; fully written each run
    mmcl_kernel<<<M_ROWS, BLOCK, 0, stream>>>(inputs, targets, partials);
    mmcl_reduce<<<1, 256, 0, stream>>>(partials, out);
}